// Round 8
// baseline (453.270 us; speedup 1.0000x reference)
//
#include <hip/hip_runtime.h>
#include <hip/hip_bf16.h>

#define DD 128
#define EDIM 16

typedef short v8s __attribute__((ext_vector_type(8)));
typedef float v4f __attribute__((ext_vector_type(4)));

// ---------- dtype-flexible helpers ----------
__device__ __forceinline__ float ldf(const void* p, int i, int bf){
  return bf ? __bfloat162float(((const __hip_bfloat16*)p)[i])
            : ((const float*)p)[i];
}
__device__ __forceinline__ float bfu_lo(unsigned u){
  unsigned b = (u & 0xffffu) << 16; float f; __builtin_memcpy(&f,&b,4); return f;
}
__device__ __forceinline__ float bfu_hi(unsigned u){
  unsigned b = u & 0xffff0000u; float f; __builtin_memcpy(&f,&b,4); return f;
}
__device__ __forceinline__ unsigned short f2bf(float f){   // RNE f32->bf16 bits
  unsigned u; __builtin_memcpy(&u,&f,4);
  unsigned r = (u + 0x7fffu + ((u>>16)&1u)) >> 16;
  return (unsigned short)r;
}
__device__ __forceinline__ unsigned packbf(float a, float b){
  return (unsigned)f2bf(a) | ((unsigned)f2bf(b) << 16);
}

// ---------- runtime dtype detection ----------
__global__ void k_detect(const void* g1, const int* ei, int E, int* flags){
  __shared__ int nz;
  if (threadIdx.x==0) nz = 0;
  __syncthreads();
  long long total = 2LL*E;
  long long stride = (total/1024) & ~1LL;
  if (stride < 2) stride = 2;
  long long idx = (long long)threadIdx.x*stride + 1;
  if (idx < total && ei[idx] != 0) atomicAdd(&nz, 1);
  __syncthreads();
  if (threadIdx.x==0){
    unsigned w = *(const unsigned*)g1;
    flags[0] = (w == 0x3F803F80u) ? 1 : 0;
    flags[1] = (nz == 0) ? 1 : 0;
  }
}

// ---------- pre-transpose weights to bf16 ----------
__global__ void k_transB(const void* w0, const void* w1, const void* w2,
                         const void* we1, const int* __restrict__ flags,
                         short* __restrict__ Bt){
  const int bf = flags[0];
  for (int idx = blockIdx.x*blockDim.x + threadIdx.x; idx < 3*16384 + 2048;
       idx += gridDim.x*blockDim.x){
    if (idx < 3*16384){
      int m = idx >> 14, r = idx & 16383;
      int nn = r >> 7, k = r & 127;
      const void* w = (m==0) ? w0 : ((m==1) ? w1 : w2);
      Bt[idx] = (short)f2bf(ldf(w, k*DD + nn, bf));
    } else {
      int r = idx - 3*16384;
      int nn = r >> 4, k = r & 15;
      Bt[idx] = (short)f2bf(ldf(we1, k*DD + nn, bf));
    }
  }
}

// ---------- edge-attr moments via MFMA self-product: Ssum = A^T A ----------
__global__ __launch_bounds__(256) void k_attr_moments(
    const void* __restrict__ attr, int E, const int* __restrict__ flags,
    float* __restrict__ Ssum /*256*/, float* __restrict__ csum /*16*/)
{
  __shared__ short Ws[4*512];        // per-wave [16 cols][32 edges]
  __shared__ float sred[4][256];
  __shared__ float credu[4][16];
  const int t = threadIdx.x;
  const int wv = t >> 6, lane = t & 63, l15 = lane & 15, quad = lane >> 4;
  const int bf = flags[0];
  const int el = lane >> 1, half = lane & 1;   // edge-local 0..31, col-half
  short* W = &Ws[wv*512];

  v4f acc = (v4f){0.f,0.f,0.f,0.f};
  float cs[8];
  #pragma unroll
  for (int j=0;j<8;++j) cs[j]=0.f;

  const int nchunks = (E + 31) >> 5;
  for (int c = blockIdx.x*4 + wv; c < nchunks; c += gridDim.x*4){
    const int e = c*32 + el;
    const bool ok = (e < E);
    float f[8];
    if (bf){
      uint4 u = {0u,0u,0u,0u};
      if (ok) u = reinterpret_cast<const uint4*>(attr)[(size_t)e*2 + half];
      f[0]=bfu_lo(u.x); f[1]=bfu_hi(u.x); f[2]=bfu_lo(u.y); f[3]=bfu_hi(u.y);
      f[4]=bfu_lo(u.z); f[5]=bfu_hi(u.z); f[6]=bfu_lo(u.w); f[7]=bfu_hi(u.w);
    } else {
      float4 v0 = {0,0,0,0}, v1 = {0,0,0,0};
      if (ok){
        const float4* ap = reinterpret_cast<const float4*>(attr) +
                           (size_t)e*4 + half*2;
        v0 = ap[0]; v1 = ap[1];
      }
      f[0]=v0.x; f[1]=v0.y; f[2]=v0.z; f[3]=v0.w;
      f[4]=v1.x; f[5]=v1.y; f[6]=v1.z; f[7]=v1.w;
    }
    #pragma unroll
    for (int j=0;j<8;++j){
      cs[j] += f[j];
      W[(half*8 + j)*32 + el] = (short)f2bf(f[j]);   // transposed store
    }
    v8s a = *reinterpret_cast<const v8s*>(&W[l15*32 + quad*8]);
    acc = __builtin_amdgcn_mfma_f32_16x16x32_bf16(a, a, acc, 0,0,0);
  }

  #pragma unroll
  for (int r=0;r<4;++r) sred[wv][(quad*4 + r)*16 + l15] = acc[r];
  #pragma unroll
  for (int j=0;j<8;++j){
    #pragma unroll
    for (int off=2; off<64; off<<=1) cs[j] += __shfl_xor(cs[j], off, 64);
  }
  if (lane < 2){
    #pragma unroll
    for (int j=0;j<8;++j) credu[wv][lane*8 + j] = cs[j];
  }
  __syncthreads();
  float s = sred[0][t]+sred[1][t]+sred[2][t]+sred[3][t];
  atomicAdd(&Ssum[t], s);
  if (t < 16){
    float s2 = credu[0][t]+credu[1][t]+credu[2][t]+credu[3][t];
    atomicAdd(&csum[t], s2);
  }
}

__global__ void k_edge_bn(const void* __restrict__ w1, const void* __restrict__ g,
                          const void* __restrict__ bb,
                          const float* __restrict__ Ssum, const float* __restrict__ csum,
                          float Einv, const int* __restrict__ flags,
                          float* __restrict__ sc, float* __restrict__ sh){
  const int j = threadIdx.x;            // 128
  const int bf = flags[0];
  float w[EDIM];
  #pragma unroll
  for (int p=0;p<EDIM;++p) w[p] = ldf(w1, p*DD + j, bf);
  float mu0 = 0.f;
  #pragma unroll
  for (int p=0;p<EDIM;++p) mu0 += csum[p]*Einv*w[p];
  float s2 = 0.f;
  #pragma unroll
  for (int p=0;p<EDIM;++p){
    float acc = 0.f;
    #pragma unroll
    for (int q=0;q<EDIM;++q) acc += Ssum[p*16 + q]*w[q];
    s2 += w[p]*acc;
  }
  float var = s2*Einv - mu0*mu0;
  float scv = ldf(g, j, bf) * rsqrtf(var + 1e-5f);
  sc[j] = scv;
  sh[j] = ldf(bb, j, bf) - mu0*scv;
}

// ---------- CSR build ----------
__global__ void k_hist(const int* __restrict__ ei, int E,
                       const int* __restrict__ flags, int* __restrict__ deg){
  const int i64 = flags[1];
  const int2* ei2 = (const int2*)ei;
  for (int e = blockIdx.x*blockDim.x + threadIdx.x; e < E;
       e += gridDim.x*blockDim.x){
    int d = i64 ? ei2[E + e].x : ei[E + e];
    atomicAdd(&deg[d], 1);
  }
}

__global__ void k_scan_partial(const int* __restrict__ deg, int n,
                               int* __restrict__ bsum){
  __shared__ int red[256];
  const int t = threadIdx.x;
  const int base = blockIdx.x*1024;
  int s = 0;
  for (int i = t; i < 1024; i += 256){
    int g = base + i;
    s += (g < n) ? deg[g] : 0;
  }
  red[t] = s; __syncthreads();
  for (int off=128; off>0; off>>=1){
    if (t < off) red[t] += red[t+off];
    __syncthreads();
  }
  if (t==0) bsum[blockIdx.x] = red[0];
}

__global__ void k_scan_tops(int* __restrict__ bsum, int nb, int* __restrict__ total){
  __shared__ int buf[256];
  const int t = threadIdx.x;
  int v = (t < nb) ? bsum[t] : 0;
  buf[t] = v; __syncthreads();
  for (int off=1; off<256; off<<=1){
    int x = (t>=off) ? buf[t-off] : 0;
    __syncthreads();
    buf[t] += x; __syncthreads();
  }
  if (t < nb) bsum[t] = buf[t] - v;
  if (t == 255) *total = buf[255];
}

// scan + also fill win2node[w] = node containing CSR slot w*64
__global__ void k_scan_final(const int* __restrict__ deg, int n,
                             const int* __restrict__ bsum, const int* __restrict__ total,
                             int* __restrict__ offsets, int* __restrict__ cursor,
                             int* __restrict__ win2node){
  __shared__ int red[256];
  const int t = threadIdx.x;
  const int base = blockIdx.x*1024 + t*4;
  int v[4]; int s = 0;
  #pragma unroll
  for (int k=0;k<4;++k){
    int g = base + k;
    v[k] = (g < n) ? deg[g] : 0;
    s += v[k];
  }
  red[t] = s; __syncthreads();
  for (int off=1; off<256; off<<=1){
    int x = (t>=off) ? red[t-off] : 0;
    __syncthreads();
    red[t] += x; __syncthreads();
  }
  int ex = bsum[blockIdx.x] + red[t] - s;
  #pragma unroll
  for (int k=0;k<4;++k){
    int g = base + k;
    if (g < n){
      offsets[g] = ex; cursor[g] = ex;
      int end = ex + v[k];
      for (int w = (ex + 63) >> 6; (w << 6) < end; ++w) win2node[w] = g;
    }
    ex += v[k];
  }
  if (blockIdx.x==0 && t==0) offsets[n] = *total;
}

// scatter: se[pp] = {src, edge-id} — 8 B per slot, no payload
__global__ void k_scatter(const int* __restrict__ ei, int E,
                          const int* __restrict__ flags,
                          int* __restrict__ cursor, int2* __restrict__ se){
  const int i64 = flags[1];
  const int2* ei2 = (const int2*)ei;
  for (int e = blockIdx.x*blockDim.x + threadIdx.x; e < E;
       e += gridDim.x*blockDim.x){
    int d = i64 ? ei2[E + e].x : ei[E + e];
    int s = i64 ? ei2[e].x     : ei[e];
    int pp = atomicAdd(&cursor[d], 1);
    se[pp] = make_int2(s, e);
  }
}

// ---------- fused edge GEMM + block-level segmented aggregate ----------
// P[slot] = relu(bn(attr[eid[slot]]@w1)) via MFMA -> LDS (64x128 f32), then
// per-column segmented sums; only window-boundary nodes use atomics.
__global__ __launch_bounds__(256) void k_edgeagg(
    const void* __restrict__ attr, const int2* __restrict__ se,
    const short* __restrict__ w1t,
    const float* __restrict__ sc, const float* __restrict__ sh,
    const int* __restrict__ offsets, const int* __restrict__ win2node,
    const int* __restrict__ flags, int n, int E, float* __restrict__ Pagg)
{
  __shared__ float Ps[64*DD];        // 32 KB
  const int t = threadIdx.x;
  const int wv = t >> 6, lane = t & 63, l15 = lane & 15, quad = lane >> 4;
  const int bf = flags[0];
  const int B0 = blockIdx.x * 64;
  const int Bend = (B0 + 64 < E) ? (B0 + 64) : E;
  const int W0 = B0 + wv*16;

  v8s a = (v8s){0,0,0,0,0,0,0,0};
  if (quad < 2){
    int slot = W0 + l15;
    if (slot < E){
      int e = se[slot].y;
      if (bf){
        a = *reinterpret_cast<const v8s*>(
              (const short*)attr + (size_t)e*EDIM + quad*8);
      } else {
        const float4* ap = reinterpret_cast<const float4*>(
              (const float*)attr + (size_t)e*EDIM + quad*8);
        float4 v0 = ap[0], v1 = ap[1];
        v8s av;
        av[0]=(short)f2bf(v0.x); av[1]=(short)f2bf(v0.y);
        av[2]=(short)f2bf(v0.z); av[3]=(short)f2bf(v0.w);
        av[4]=(short)f2bf(v1.x); av[5]=(short)f2bf(v1.y);
        av[6]=(short)f2bf(v1.z); av[7]=(short)f2bf(v1.w);
        a = av;
      }
    }
  }
  const int lr0 = wv*16 + quad*4;     // local row base for C-layout
  #pragma unroll
  for (int cg=0;cg<8;++cg){
    v8s b = (v8s){0,0,0,0,0,0,0,0};
    if (quad < 2)
      b = *reinterpret_cast<const v8s*>(&w1t[(cg*16+l15)*EDIM + quad*8]);
    v4f acc = (v4f){0.f,0.f,0.f,0.f};
    acc = __builtin_amdgcn_mfma_f32_16x16x32_bf16(a, b, acc, 0,0,0);
    const float scv = sc[cg*16+l15], shv = sh[cg*16+l15];
    #pragma unroll
    for (int reg=0;reg<4;++reg)
      Ps[(lr0+reg)*DD + cg*16 + l15] = fmaxf(fmaf(acc[reg], scv, shv), 0.f);
  }
  __syncthreads();

  const int c = t & 127, half = t >> 7;
  const int i0 = win2node[blockIdx.x];
  for (int idx = i0 + half; idx < n; idx += 2){
    int nb = offsets[idx], ne = offsets[idx+1];
    if (nb >= Bend) break;
    int s0 = nb > B0 ? nb : B0;
    int s1 = ne < Bend ? ne : Bend;
    if (s1 <= s0) continue;          // degree-0 node inside window
    float sum = 0.f;
    for (int s = s0; s < s1; ++s) sum += Ps[(s - B0)*DD + c];
    if (nb < B0 || ne > Bend) atomicAdd(&Pagg[(size_t)idx*DD + c], sum);
    else                      Pagg[(size_t)idx*DD + c] = sum;
  }
}

// ---------- z = h_new + gather-sum of h_new[src] (4 rows/issue) ----------
__global__ __launch_bounds__(256) void k_gather_z(
    const uint4* __restrict__ hnew16, const int* __restrict__ offsets,
    const int2* __restrict__ se, int n, uint4* __restrict__ zH16)
{
  const int wv = threadIdx.x >> 6, lane = threadIdx.x & 63;
  const int g = lane >> 4, c16 = lane & 15;
  for (int i = blockIdx.x*4 + wv; i < n; i += gridDim.x*4){
    const int beg = offsets[i], end = offsets[i+1];
    float a0=0.f,a1=0.f,a2=0.f,a3=0.f,a4=0.f,a5=0.f,a6=0.f,a7=0.f;
    int c0 = beg;
    for (; c0 + 8 <= end; c0 += 8){
      int s1 = se[c0 + g].x;
      int s2 = se[c0 + 4 + g].x;
      uint4 u = hnew16[(size_t)s1*16 + c16];
      uint4 v = hnew16[(size_t)s2*16 + c16];
      a0 += bfu_lo(u.x)+bfu_lo(v.x); a1 += bfu_hi(u.x)+bfu_hi(v.x);
      a2 += bfu_lo(u.y)+bfu_lo(v.y); a3 += bfu_hi(u.y)+bfu_hi(v.y);
      a4 += bfu_lo(u.z)+bfu_lo(v.z); a5 += bfu_hi(u.z)+bfu_hi(v.z);
      a6 += bfu_lo(u.w)+bfu_lo(v.w); a7 += bfu_hi(u.w)+bfu_hi(v.w);
    }
    for (; c0 < end; c0 += 4){
      int r = c0 + g;
      if (r < end){
        uint4 u = hnew16[(size_t)se[r].x*16 + c16];
        a0 += bfu_lo(u.x); a1 += bfu_hi(u.x);
        a2 += bfu_lo(u.y); a3 += bfu_hi(u.y);
        a4 += bfu_lo(u.z); a5 += bfu_hi(u.z);
        a6 += bfu_lo(u.w); a7 += bfu_hi(u.w);
      }
    }
    a0 += __shfl_xor(a0,16,64); a1 += __shfl_xor(a1,16,64);
    a2 += __shfl_xor(a2,16,64); a3 += __shfl_xor(a3,16,64);
    a4 += __shfl_xor(a4,16,64); a5 += __shfl_xor(a5,16,64);
    a6 += __shfl_xor(a6,16,64); a7 += __shfl_xor(a7,16,64);
    a0 += __shfl_xor(a0,32,64); a1 += __shfl_xor(a1,32,64);
    a2 += __shfl_xor(a2,32,64); a3 += __shfl_xor(a3,32,64);
    a4 += __shfl_xor(a4,32,64); a5 += __shfl_xor(a5,32,64);
    a6 += __shfl_xor(a6,32,64); a7 += __shfl_xor(a7,32,64);
    if (lane < 16){
      uint4 m = hnew16[(size_t)i*16 + lane];
      uint4 o;
      o.x = packbf(a0+bfu_lo(m.x), a1+bfu_hi(m.x));
      o.y = packbf(a2+bfu_lo(m.y), a3+bfu_hi(m.y));
      o.z = packbf(a4+bfu_lo(m.z), a5+bfu_hi(m.z));
      o.w = packbf(a6+bfu_lo(m.w), a7+bfu_hi(m.w));
      zH16[(size_t)i*16 + lane] = o;
    }
  }
}

// ---------- LDS-free MFMA GEMM: out(bf16) = f(A)@B + epilogue ----------
__global__ __launch_bounds__(256) void k_gemm_mfma(
    const short* __restrict__ A, const float* __restrict__ Af32,
    const short* __restrict__ Bt, const void* __restrict__ bias,
    const float* __restrict__ psc, const float* __restrict__ psh,
    const int* __restrict__ deg, const void* __restrict__ H,
    const int* __restrict__ flags, int n,
    __hip_bfloat16* __restrict__ out, float* __restrict__ stats, int mode)
{
  __shared__ float sb[256];
  const int t = threadIdx.x;
  const int bfi = flags[0];
  sb[t] = 0.f;
  __syncthreads();
  const int wv = t >> 6, lane = t & 63, l15 = lane & 15, quad = lane >> 4;
  const int R0 = blockIdx.x*64 + wv*16;

  v8s a[4];
  {
    const int arow = R0 + l15;
    const bool ok = (arow < n);
    #pragma unroll
    for (int ks=0;ks<4;++ks){
      const int k0 = ks*32 + quad*8;
      float f[8];
      if (Af32){
        float4 v0 = {0,0,0,0}, v1 = {0,0,0,0};
        if (ok){
          const float4* ap = reinterpret_cast<const float4*>(
              Af32 + (size_t)arow*DD + k0);
          v0 = ap[0]; v1 = ap[1];
        }
        f[0]=v0.x; f[1]=v0.y; f[2]=v0.z; f[3]=v0.w;
        f[4]=v1.x; f[5]=v1.y; f[6]=v1.z; f[7]=v1.w;
        v8s av;
        #pragma unroll
        for (int j=0;j<8;++j) av[j] = (short)f2bf(f[j]);
        a[ks] = av;
      } else {
        uint4 u = {0u,0u,0u,0u};
        if (ok) u = *reinterpret_cast<const uint4*>(&A[(size_t)arow*DD + k0]);
        if (psc){
          f[0]=bfu_lo(u.x); f[1]=bfu_hi(u.x); f[2]=bfu_lo(u.y); f[3]=bfu_hi(u.y);
          f[4]=bfu_lo(u.z); f[5]=bfu_hi(u.z); f[6]=bfu_lo(u.w); f[7]=bfu_hi(u.w);
          v8s av;
          #pragma unroll
          for (int j=0;j<8;++j)
            av[j] = (short)f2bf(fmaxf(fmaf(f[j], psc[k0+j], psh[k0+j]), 0.f));
          a[ks] = av;
        } else {
          a[ks] = *reinterpret_cast<v8s*>(&u);
        }
      }
    }
  }

  v4f acc[8];
  #pragma unroll
  for (int cg=0;cg<8;++cg) acc[cg] = (v4f){0.f,0.f,0.f,0.f};
  #pragma unroll
  for (int ks=0;ks<4;++ks){
    #pragma unroll
    for (int cg=0;cg<8;++cg){
      v8s b = *reinterpret_cast<const v8s*>(
                &Bt[(cg*16+l15)*DD + ks*32 + quad*8]);
      acc[cg] = __builtin_amdgcn_mfma_f32_16x16x32_bf16(a[ks], b, acc[cg], 0,0,0);
    }
  }

  float bc[8];
  #pragma unroll
  for (int cg=0;cg<8;++cg) bc[cg] = ldf(bias, cg*16 + l15, bfi);
  float ss[8], sq[8];
  #pragma unroll
  for (int cg=0;cg<8;++cg){ ss[cg]=0.f; sq[cg]=0.f; }

  #pragma unroll
  for (int reg=0;reg<4;++reg){
    const int row = R0 + quad*4 + reg;
    if (row < n){
      float degf = (mode==1) ? (float)deg[row] : 0.f;
      #pragma unroll
      for (int cg=0;cg<8;++cg){
        const int col = cg*16 + l15;
        float x = acc[cg][reg];
        if (mode==1) x = fmaf(degf, bc[cg], x) + ldf(H, (size_t)row*DD + col, bfi);
        else         x += bc[cg];
        out[(size_t)row*DD + col] = __float2bfloat16(x);
        ss[cg] += x; sq[cg] += x*x;
      }
    }
  }

  if (stats){
    #pragma unroll
    for (int cg=0;cg<8;++cg){
      float s = ss[cg], q = sq[cg];
      s += __shfl_xor(s, 16, 64); s += __shfl_xor(s, 32, 64);
      q += __shfl_xor(q, 16, 64); q += __shfl_xor(q, 32, 64);
      if (quad == 0){
        atomicAdd(&sb[cg*16 + l15], s);
        atomicAdd(&sb[128 + cg*16 + l15], q);
      }
    }
    __syncthreads();
    atomicAdd(&stats[t], sb[t]);
  }
}

__global__ void k_bn_params(const float* __restrict__ stats, const void* __restrict__ g,
                            const void* __restrict__ bb, const int* __restrict__ flags,
                            float inv_n, float* __restrict__ sc, float* __restrict__ sh){
  const int j = threadIdx.x;                // 128
  const int bf = flags[0];
  float mean = stats[j]*inv_n;
  float var  = stats[DD+j]*inv_n - mean*mean;
  float s = ldf(g, j, bf) * rsqrtf(var + 1e-5f);
  sc[j] = s;
  sh[j] = ldf(bb, j, bf) - mean*s;
}

__global__ void k_final(const unsigned* __restrict__ yH,
                        const float* __restrict__ sc, const float* __restrict__ sh,
                        int n, const int* __restrict__ flags, void* __restrict__ out){
  const int bf = flags[0];
  const int nw = n*64;
  for (int i = blockIdx.x*blockDim.x + threadIdx.x; i < nw;
       i += gridDim.x*blockDim.x){
    const int j0 = (i & 63)*2;
    unsigned u = yH[i];
    float v0 = fmaxf(fmaf(bfu_lo(u), sc[j0],   sh[j0]),   0.f);
    float v1 = fmaxf(fmaf(bfu_hi(u), sc[j0+1], sh[j0+1]), 0.f);
    if (bf){
      ((unsigned*)out)[i] = packbf(v0, v1);
    } else {
      *reinterpret_cast<float2*>((float*)out + 2*(size_t)i) = make_float2(v0, v1);
    }
  }
}

extern "C" void kernel_launch(void* const* d_in, const int* in_sizes, int n_in,
                              void* d_out, int out_size, void* d_ws, size_t ws_size,
                              hipStream_t stream)
{
  const void* h       = d_in[0];
  const int*  ei      = (const int*)d_in[1];
  const void* attr    = d_in[2];
  const void* ee_w1   = d_in[3];
  const void* ee_g1   = d_in[5];
  const void* ee_bb1  = d_in[6];
  const void* ee_w2   = d_in[7];
  const void* ee_b2   = d_in[8];
  const void* mlp_w1  = d_in[9];
  const void* mlp_b1  = d_in[10];
  const void* mlp_g1  = d_in[11];
  const void* mlp_bb1 = d_in[12];
  const void* mlp_w2  = d_in[13];
  const void* mlp_b2  = d_in[14];
  const void* mlp_g2  = d_in[15];
  const void* mlp_bb2 = d_in[16];

  const int N = in_sizes[0] / DD;
  const int E = in_sizes[1] / 2;
  const int nb = (N + 1023) / 1024;
  const int e64 = (E + 63) / 64;      // edge windows

  char* p = (char*)d_ws;
  auto alloc = [&](size_t bytes)->char*{
    char* r = p;
    p += (bytes + 255) & ~size_t(255);
    return r;
  };
  int* flags = (int*)alloc(8);
  // zero region: deg | csum(16) | Ssum(256) | stats1(256) | stats2(256) | Pagg
  char* zbase = p;
  int*   deg    = (int*)  zbase;
  float* csum   = (float*)(zbase + (size_t)N*4);
  float* Ssum   = (float*)(zbase + (size_t)N*4 + 64);
  float* stats1 = (float*)(zbase + (size_t)N*4 + 64 + 1024);
  float* stats2 = (float*)(zbase + (size_t)N*4 + 64 + 2048);
  float* Pagg   = (float*)(zbase + (size_t)N*4 + 64 + 3072);
  size_t zlen   = (size_t)N*4 + 64 + 3072 + (size_t)N*DD*4;
  p += (zlen + 255) & ~size_t(255);
  int*   bsum     = (int*)  alloc(256*4);
  int*   total    = (int*)  alloc(64);
  int*   offsets  = (int*)  alloc((size_t)(N+1)*4);
  int*   cursor   = (int*)  alloc((size_t)N*4);
  int*   win2node = (int*)  alloc((size_t)e64*4);
  int2*  se       = (int2*) alloc((size_t)E*8);
  short* Bt      = (short*)alloc((size_t)(3*DD*DD + DD*EDIM)*2);
  short* w1t     = Bt + 3*DD*DD;
  float* ebn_sc  = (float*)alloc(512);
  float* ebn_sh  = (float*)alloc(512);
  float* sc1     = (float*)alloc(512);
  float* sh1     = (float*)alloc(512);
  float* sc2     = (float*)alloc(512);
  float* sh2     = (float*)alloc(512);
  short* hnewH   = (short*)alloc((size_t)N*DD*2);
  short* zH      = (short*)alloc((size_t)N*DD*2);
  short* y1H     = (short*)alloc((size_t)N*DD*2);
  short* y2H     = (short*)alloc((size_t)N*DD*2);
  (void)ws_size; (void)n_in; (void)out_size;

  const int g64  = (N + 63) / 64;     // gemm grid
  const int gseg = (N + 15) / 16;     // gather grid (wave per node)

  hipMemsetAsync(zbase, 0, zlen, stream);
  k_detect<<<1, 1024, 0, stream>>>(ee_g1, ei, E, flags);
  k_transB<<<208, 256, 0, stream>>>(ee_w2, mlp_w1, mlp_w2, ee_w1, flags, Bt);
  k_attr_moments<<<256, 256, 0, stream>>>(attr, E, flags, Ssum, csum);
  k_edge_bn<<<1, 128, 0, stream>>>(ee_w1, ee_g1, ee_bb1, Ssum, csum,
                                   1.0f/(float)E, flags, ebn_sc, ebn_sh);
  k_hist<<<1024, 256, 0, stream>>>(ei, E, flags, deg);
  k_scan_partial<<<nb, 256, 0, stream>>>(deg, N, bsum);
  k_scan_tops<<<1, 256, 0, stream>>>(bsum, nb, total);
  k_scan_final<<<nb, 256, 0, stream>>>(deg, N, bsum, total, offsets, cursor,
                                       win2node);
  k_scatter<<<1024, 256, 0, stream>>>(ei, E, flags, cursor, se);

  // fused edge encoder + block-level node aggregate (f32 Pagg)
  k_edgeagg<<<e64, 256, 0, stream>>>(attr, se, w1t, ebn_sc, ebn_sh,
                                     offsets, win2node, flags, N, E, Pagg);

  // h_new = h + Pagg@ee_w2 + deg*ee_b2
  k_gemm_mfma<<<g64, 256, 0, stream>>>(nullptr, Pagg, Bt, ee_b2,
                                       nullptr, nullptr, deg, h, flags, N,
                                       (__hip_bfloat16*)hnewH, nullptr, 1);
  // z = h_new + gather
  k_gather_z<<<gseg, 256, 0, stream>>>((const uint4*)hnewH, offsets, se, N,
                                       (uint4*)zH);
  // y1 = z@mlp_w1 + b1 (+stats)
  k_gemm_mfma<<<g64, 256, 0, stream>>>(zH, nullptr, Bt + 16384, mlp_b1,
                                       nullptr, nullptr, nullptr, nullptr,
                                       flags, N, (__hip_bfloat16*)y1H, stats1, 0);
  k_bn_params<<<1, 128, 0, stream>>>(stats1, mlp_g1, mlp_bb1, flags,
                                     1.0f/(float)N, sc1, sh1);
  // y2 = relu(bn(y1))@mlp_w2 + b2 (+stats)
  k_gemm_mfma<<<g64, 256, 0, stream>>>(y1H, nullptr, Bt + 32768, mlp_b2,
                                       sc1, sh1, nullptr, nullptr,
                                       flags, N, (__hip_bfloat16*)y2H, stats2, 0);
  k_bn_params<<<1, 128, 0, stream>>>(stats2, mlp_g2, mlp_bb2, flags,
                                     1.0f/(float)N, sc2, sh2);

  k_final<<<2048, 256, 0, stream>>>((const unsigned*)y2H, sc2, sh2,
                                    N, flags, d_out);
}

// Round 9
// 440.994 us; speedup vs baseline: 1.0278x; 1.0278x over previous
//
#include <hip/hip_runtime.h>
#include <hip/hip_bf16.h>

#define DD 128
#define EDIM 16
#define WPB 4          // edge windows (64 slots) per k_edgeagg block
#define PSP 132        // padded LDS row stride (floats): 4*132%32=16 -> 2-way

typedef short v8s __attribute__((ext_vector_type(8)));
typedef float v4f __attribute__((ext_vector_type(4)));

// ---------- dtype-flexible helpers ----------
__device__ __forceinline__ float ldf(const void* p, int i, int bf){
  return bf ? __bfloat162float(((const __hip_bfloat16*)p)[i])
            : ((const float*)p)[i];
}
__device__ __forceinline__ float bfu_lo(unsigned u){
  unsigned b = (u & 0xffffu) << 16; float f; __builtin_memcpy(&f,&b,4); return f;
}
__device__ __forceinline__ float bfu_hi(unsigned u){
  unsigned b = u & 0xffff0000u; float f; __builtin_memcpy(&f,&b,4); return f;
}
__device__ __forceinline__ unsigned short f2bf(float f){   // RNE f32->bf16 bits
  unsigned u; __builtin_memcpy(&u,&f,4);
  unsigned r = (u + 0x7fffu + ((u>>16)&1u)) >> 16;
  return (unsigned short)r;
}
__device__ __forceinline__ unsigned packbf(float a, float b){
  return (unsigned)f2bf(a) | ((unsigned)f2bf(b) << 16);
}

// ---------- runtime dtype detection ----------
__global__ void k_detect(const void* g1, const int* ei, int E, int* flags){
  __shared__ int nz;
  if (threadIdx.x==0) nz = 0;
  __syncthreads();
  long long total = 2LL*E;
  long long stride = (total/1024) & ~1LL;
  if (stride < 2) stride = 2;
  long long idx = (long long)threadIdx.x*stride + 1;
  if (idx < total && ei[idx] != 0) atomicAdd(&nz, 1);
  __syncthreads();
  if (threadIdx.x==0){
    unsigned w = *(const unsigned*)g1;
    flags[0] = (w == 0x3F803F80u) ? 1 : 0;
    flags[1] = (nz == 0) ? 1 : 0;
  }
}

// ---------- pre-transpose weights to bf16 ----------
__global__ void k_transB(const void* w0, const void* w1, const void* w2,
                         const void* we1, const int* __restrict__ flags,
                         short* __restrict__ Bt){
  const int bf = flags[0];
  for (int idx = blockIdx.x*blockDim.x + threadIdx.x; idx < 3*16384 + 2048;
       idx += gridDim.x*blockDim.x){
    if (idx < 3*16384){
      int m = idx >> 14, r = idx & 16383;
      int nn = r >> 7, k = r & 127;
      const void* w = (m==0) ? w0 : ((m==1) ? w1 : w2);
      Bt[idx] = (short)f2bf(ldf(w, k*DD + nn, bf));
    } else {
      int r = idx - 3*16384;
      int nn = r >> 4, k = r & 15;
      Bt[idx] = (short)f2bf(ldf(we1, k*DD + nn, bf));
    }
  }
}

// ---------- edge-attr moments via MFMA self-product: Ssum = A^T A ----------
__global__ __launch_bounds__(256) void k_attr_moments(
    const void* __restrict__ attr, int E, const int* __restrict__ flags,
    float* __restrict__ Ssum /*256*/, float* __restrict__ csum /*16*/)
{
  __shared__ short Ws[4*512];        // per-wave [16 cols][32 edges]
  __shared__ float sred[4][256];
  __shared__ float credu[4][16];
  const int t = threadIdx.x;
  const int wv = t >> 6, lane = t & 63, l15 = lane & 15, quad = lane >> 4;
  const int bf = flags[0];
  const int el = lane >> 1, half = lane & 1;   // edge-local 0..31, col-half
  short* W = &Ws[wv*512];

  v4f acc = (v4f){0.f,0.f,0.f,0.f};
  float cs[8];
  #pragma unroll
  for (int j=0;j<8;++j) cs[j]=0.f;

  const int nchunks = (E + 31) >> 5;
  for (int c = blockIdx.x*4 + wv; c < nchunks; c += gridDim.x*4){
    const int e = c*32 + el;
    const bool ok = (e < E);
    float f[8];
    if (bf){
      uint4 u = {0u,0u,0u,0u};
      if (ok) u = reinterpret_cast<const uint4*>(attr)[(size_t)e*2 + half];
      f[0]=bfu_lo(u.x); f[1]=bfu_hi(u.x); f[2]=bfu_lo(u.y); f[3]=bfu_hi(u.y);
      f[4]=bfu_lo(u.z); f[5]=bfu_hi(u.z); f[6]=bfu_lo(u.w); f[7]=bfu_hi(u.w);
    } else {
      float4 v0 = {0,0,0,0}, v1 = {0,0,0,0};
      if (ok){
        const float4* ap = reinterpret_cast<const float4*>(attr) +
                           (size_t)e*4 + half*2;
        v0 = ap[0]; v1 = ap[1];
      }
      f[0]=v0.x; f[1]=v0.y; f[2]=v0.z; f[3]=v0.w;
      f[4]=v1.x; f[5]=v1.y; f[6]=v1.z; f[7]=v1.w;
    }
    #pragma unroll
    for (int j=0;j<8;++j){
      cs[j] += f[j];
      W[(half*8 + j)*32 + el] = (short)f2bf(f[j]);   // transposed store
    }
    v8s a = *reinterpret_cast<const v8s*>(&W[l15*32 + quad*8]);
    acc = __builtin_amdgcn_mfma_f32_16x16x32_bf16(a, a, acc, 0,0,0);
  }

  #pragma unroll
  for (int r=0;r<4;++r) sred[wv][(quad*4 + r)*16 + l15] = acc[r];
  #pragma unroll
  for (int j=0;j<8;++j){
    #pragma unroll
    for (int off=2; off<64; off<<=1) cs[j] += __shfl_xor(cs[j], off, 64);
  }
  if (lane < 2){
    #pragma unroll
    for (int j=0;j<8;++j) credu[wv][lane*8 + j] = cs[j];
  }
  __syncthreads();
  float s = sred[0][t]+sred[1][t]+sred[2][t]+sred[3][t];
  atomicAdd(&Ssum[t], s);
  if (t < 16){
    float s2 = credu[0][t]+credu[1][t]+credu[2][t]+credu[3][t];
    atomicAdd(&csum[t], s2);
  }
}

__global__ void k_edge_bn(const void* __restrict__ w1, const void* __restrict__ g,
                          const void* __restrict__ bb,
                          const float* __restrict__ Ssum, const float* __restrict__ csum,
                          float Einv, const int* __restrict__ flags,
                          float* __restrict__ sc, float* __restrict__ sh){
  const int j = threadIdx.x;            // 128
  const int bf = flags[0];
  float w[EDIM];
  #pragma unroll
  for (int p=0;p<EDIM;++p) w[p] = ldf(w1, p*DD + j, bf);
  float mu0 = 0.f;
  #pragma unroll
  for (int p=0;p<EDIM;++p) mu0 += csum[p]*Einv*w[p];
  float s2 = 0.f;
  #pragma unroll
  for (int p=0;p<EDIM;++p){
    float acc = 0.f;
    #pragma unroll
    for (int q=0;q<EDIM;++q) acc += Ssum[p*16 + q]*w[q];
    s2 += w[p]*acc;
  }
  float var = s2*Einv - mu0*mu0;
  float scv = ldf(g, j, bf) * rsqrtf(var + 1e-5f);
  sc[j] = scv;
  sh[j] = ldf(bb, j, bf) - mu0*scv;
}

// ---------- CSR build ----------
__global__ void k_hist(const int* __restrict__ ei, int E,
                       const int* __restrict__ flags, int* __restrict__ deg){
  const int i64 = flags[1];
  const int2* ei2 = (const int2*)ei;
  for (int e = blockIdx.x*blockDim.x + threadIdx.x; e < E;
       e += gridDim.x*blockDim.x){
    int d = i64 ? ei2[E + e].x : ei[E + e];
    atomicAdd(&deg[d], 1);
  }
}

__global__ void k_scan_partial(const int* __restrict__ deg, int n,
                               int* __restrict__ bsum){
  __shared__ int red[256];
  const int t = threadIdx.x;
  const int base = blockIdx.x*1024;
  int s = 0;
  for (int i = t; i < 1024; i += 256){
    int g = base + i;
    s += (g < n) ? deg[g] : 0;
  }
  red[t] = s; __syncthreads();
  for (int off=128; off>0; off>>=1){
    if (t < off) red[t] += red[t+off];
    __syncthreads();
  }
  if (t==0) bsum[blockIdx.x] = red[0];
}

__global__ void k_scan_tops(int* __restrict__ bsum, int nb, int* __restrict__ total){
  __shared__ int buf[256];
  const int t = threadIdx.x;
  int v = (t < nb) ? bsum[t] : 0;
  buf[t] = v; __syncthreads();
  for (int off=1; off<256; off<<=1){
    int x = (t>=off) ? buf[t-off] : 0;
    __syncthreads();
    buf[t] += x; __syncthreads();
  }
  if (t < nb) bsum[t] = buf[t] - v;
  if (t == 255) *total = buf[255];
}

// scan + also fill win2node[w] = node containing CSR slot w*64
__global__ void k_scan_final(const int* __restrict__ deg, int n,
                             const int* __restrict__ bsum, const int* __restrict__ total,
                             int* __restrict__ offsets, int* __restrict__ cursor,
                             int* __restrict__ win2node){
  __shared__ int red[256];
  const int t = threadIdx.x;
  const int base = blockIdx.x*1024 + t*4;
  int v[4]; int s = 0;
  #pragma unroll
  for (int k=0;k<4;++k){
    int g = base + k;
    v[k] = (g < n) ? deg[g] : 0;
    s += v[k];
  }
  red[t] = s; __syncthreads();
  for (int off=1; off<256; off<<=1){
    int x = (t>=off) ? red[t-off] : 0;
    __syncthreads();
    red[t] += x; __syncthreads();
  }
  int ex = bsum[blockIdx.x] + red[t] - s;
  #pragma unroll
  for (int k=0;k<4;++k){
    int g = base + k;
    if (g < n){
      offsets[g] = ex; cursor[g] = ex;
      int end = ex + v[k];
      for (int w = (ex + 63) >> 6; (w << 6) < end; ++w) win2node[w] = g;
    }
    ex += v[k];
  }
  if (blockIdx.x==0 && t==0) offsets[n] = *total;
}

// scatter: se[pp] = {src, edge-id} — 8 B per slot, no payload
__global__ void k_scatter(const int* __restrict__ ei, int E,
                          const int* __restrict__ flags,
                          int* __restrict__ cursor, int2* __restrict__ se){
  const int i64 = flags[1];
  const int2* ei2 = (const int2*)ei;
  for (int e = blockIdx.x*blockDim.x + threadIdx.x; e < E;
       e += gridDim.x*blockDim.x){
    int d = i64 ? ei2[E + e].x : ei[E + e];
    int s = i64 ? ei2[e].x     : ei[e];
    int pp = atomicAdd(&cursor[d], 1);
    se[pp] = make_int2(s, e);
  }
}

// ---------- fused edge GEMM + block-level segmented aggregate ----------
// 4 windows of 64 CSR slots per block; all attr fragments prefetched up front
// to overlap the se->attr dependent-load chains with compute/reduce phases.
// LDS row stride PSP=132 -> MFMA stores are 2-way-aliased only (free).
__global__ __launch_bounds__(256) void k_edgeagg(
    const void* __restrict__ attr, const int2* __restrict__ se,
    const short* __restrict__ w1t,
    const float* __restrict__ sc, const float* __restrict__ sh,
    const int* __restrict__ offsets, const int* __restrict__ win2node,
    const int* __restrict__ flags, int n, int E, float* __restrict__ Pagg)
{
  __shared__ float Ps[64*PSP];       // 33.8 KB
  const int t = threadIdx.x;
  const int wv = t >> 6, lane = t & 63, l15 = lane & 15, quad = lane >> 4;
  const int bf = flags[0];
  const int G0 = blockIdx.x * (64*WPB);
  if (G0 >= E) return;

  // prefetch all 4 windows' A-fragments (concurrent se->attr chains)
  v8s afrag[WPB];
  #pragma unroll
  for (int w=0; w<WPB; ++w){
    afrag[w] = (v8s){0,0,0,0,0,0,0,0};
    if (quad < 2){
      int slot = G0 + w*64 + wv*16 + l15;
      if (slot < E){
        int e = se[slot].y;
        if (bf){
          afrag[w] = *reinterpret_cast<const v8s*>(
                (const short*)attr + (size_t)e*EDIM + quad*8);
        } else {
          const float4* ap = reinterpret_cast<const float4*>(
                (const float*)attr + (size_t)e*EDIM + quad*8);
          float4 v0 = ap[0], v1 = ap[1];
          v8s av;
          av[0]=(short)f2bf(v0.x); av[1]=(short)f2bf(v0.y);
          av[2]=(short)f2bf(v0.z); av[3]=(short)f2bf(v0.w);
          av[4]=(short)f2bf(v1.x); av[5]=(short)f2bf(v1.y);
          av[6]=(short)f2bf(v1.z); av[7]=(short)f2bf(v1.w);
          afrag[w] = av;
        }
      }
    }
  }

  // hoisted B fragments + BN params
  v8s bfrag[8];
  float scv[8], shv[8];
  #pragma unroll
  for (int cg=0;cg<8;++cg){
    bfrag[cg] = (v8s){0,0,0,0,0,0,0,0};
    if (quad < 2)
      bfrag[cg] = *reinterpret_cast<const v8s*>(&w1t[(cg*16+l15)*EDIM + quad*8]);
    scv[cg] = sc[cg*16+l15];
    shv[cg] = sh[cg*16+l15];
  }

  const int lr0 = wv*16 + quad*4;
  const int c = t & 127, half = t >> 7;

  #pragma unroll
  for (int w=0; w<WPB; ++w){
    const int B0 = G0 + w*64;
    if (B0 >= E) break;
    const int Bend = (B0 + 64 < E) ? (B0 + 64) : E;

    #pragma unroll
    for (int cg=0;cg<8;++cg){
      v4f acc = (v4f){0.f,0.f,0.f,0.f};
      acc = __builtin_amdgcn_mfma_f32_16x16x32_bf16(afrag[w], bfrag[cg], acc, 0,0,0);
      #pragma unroll
      for (int reg=0;reg<4;++reg)
        Ps[(lr0+reg)*PSP + cg*16 + l15] =
            fmaxf(fmaf(acc[reg], scv[cg], shv[cg]), 0.f);
    }
    __syncthreads();

    const int i0 = win2node[blockIdx.x*WPB + w];
    for (int idx = i0 + half; idx < n; idx += 2){
      int nb = offsets[idx], ne = offsets[idx+1];
      if (nb >= Bend) break;
      int s0 = nb > B0 ? nb : B0;
      int s1 = ne < Bend ? ne : Bend;
      if (s1 <= s0) continue;        // degree-0 node inside window
      float sum = 0.f;
      for (int s = s0; s < s1; ++s) sum += Ps[(s - B0)*PSP + c];
      if (nb < B0 || ne > Bend) atomicAdd(&Pagg[(size_t)idx*DD + c], sum);
      else                      Pagg[(size_t)idx*DD + c] = sum;
    }
    __syncthreads();
  }
}

// ---------- z = h_new + gather-sum of h_new[src] (4 rows/issue) ----------
__global__ __launch_bounds__(256) void k_gather_z(
    const uint4* __restrict__ hnew16, const int* __restrict__ offsets,
    const int2* __restrict__ se, int n, uint4* __restrict__ zH16)
{
  const int wv = threadIdx.x >> 6, lane = threadIdx.x & 63;
  const int g = lane >> 4, c16 = lane & 15;
  for (int i = blockIdx.x*4 + wv; i < n; i += gridDim.x*4){
    const int beg = offsets[i], end = offsets[i+1];
    float a0=0.f,a1=0.f,a2=0.f,a3=0.f,a4=0.f,a5=0.f,a6=0.f,a7=0.f;
    int c0 = beg;
    for (; c0 + 8 <= end; c0 += 8){
      int s1 = se[c0 + g].x;
      int s2 = se[c0 + 4 + g].x;
      uint4 u = hnew16[(size_t)s1*16 + c16];
      uint4 v = hnew16[(size_t)s2*16 + c16];
      a0 += bfu_lo(u.x)+bfu_lo(v.x); a1 += bfu_hi(u.x)+bfu_hi(v.x);
      a2 += bfu_lo(u.y)+bfu_lo(v.y); a3 += bfu_hi(u.y)+bfu_hi(v.y);
      a4 += bfu_lo(u.z)+bfu_lo(v.z); a5 += bfu_hi(u.z)+bfu_hi(v.z);
      a6 += bfu_lo(u.w)+bfu_lo(v.w); a7 += bfu_hi(u.w)+bfu_hi(v.w);
    }
    for (; c0 < end; c0 += 4){
      int r = c0 + g;
      if (r < end){
        uint4 u = hnew16[(size_t)se[r].x*16 + c16];
        a0 += bfu_lo(u.x); a1 += bfu_hi(u.x);
        a2 += bfu_lo(u.y); a3 += bfu_hi(u.y);
        a4 += bfu_lo(u.z); a5 += bfu_hi(u.z);
        a6 += bfu_lo(u.w); a7 += bfu_hi(u.w);
      }
    }
    a0 += __shfl_xor(a0,16,64); a1 += __shfl_xor(a1,16,64);
    a2 += __shfl_xor(a2,16,64); a3 += __shfl_xor(a3,16,64);
    a4 += __shfl_xor(a4,16,64); a5 += __shfl_xor(a5,16,64);
    a6 += __shfl_xor(a6,16,64); a7 += __shfl_xor(a7,16,64);
    a0 += __shfl_xor(a0,32,64); a1 += __shfl_xor(a1,32,64);
    a2 += __shfl_xor(a2,32,64); a3 += __shfl_xor(a3,32,64);
    a4 += __shfl_xor(a4,32,64); a5 += __shfl_xor(a5,32,64);
    a6 += __shfl_xor(a6,32,64); a7 += __shfl_xor(a7,32,64);
    if (lane < 16){
      uint4 m = hnew16[(size_t)i*16 + lane];
      uint4 o;
      o.x = packbf(a0+bfu_lo(m.x), a1+bfu_hi(m.x));
      o.y = packbf(a2+bfu_lo(m.y), a3+bfu_hi(m.y));
      o.z = packbf(a4+bfu_lo(m.z), a5+bfu_hi(m.z));
      o.w = packbf(a6+bfu_lo(m.w), a7+bfu_hi(m.w));
      zH16[(size_t)i*16 + lane] = o;
    }
  }
}

// ---------- LDS-free MFMA GEMM: out(bf16) = f(A)@B + epilogue ----------
__global__ __launch_bounds__(256) void k_gemm_mfma(
    const short* __restrict__ A, const float* __restrict__ Af32,
    const short* __restrict__ Bt, const void* __restrict__ bias,
    const float* __restrict__ psc, const float* __restrict__ psh,
    const int* __restrict__ deg, const void* __restrict__ H,
    const int* __restrict__ flags, int n,
    __hip_bfloat16* __restrict__ out, float* __restrict__ stats, int mode)
{
  __shared__ float sb[256];
  const int t = threadIdx.x;
  const int bfi = flags[0];
  sb[t] = 0.f;
  __syncthreads();
  const int wv = t >> 6, lane = t & 63, l15 = lane & 15, quad = lane >> 4;
  const int R0 = blockIdx.x*64 + wv*16;

  v8s a[4];
  {
    const int arow = R0 + l15;
    const bool ok = (arow < n);
    #pragma unroll
    for (int ks=0;ks<4;++ks){
      const int k0 = ks*32 + quad*8;
      float f[8];
      if (Af32){
        float4 v0 = {0,0,0,0}, v1 = {0,0,0,0};
        if (ok){
          const float4* ap = reinterpret_cast<const float4*>(
              Af32 + (size_t)arow*DD + k0);
          v0 = ap[0]; v1 = ap[1];
        }
        f[0]=v0.x; f[1]=v0.y; f[2]=v0.z; f[3]=v0.w;
        f[4]=v1.x; f[5]=v1.y; f[6]=v1.z; f[7]=v1.w;
        v8s av;
        #pragma unroll
        for (int j=0;j<8;++j) av[j] = (short)f2bf(f[j]);
        a[ks] = av;
      } else {
        uint4 u = {0u,0u,0u,0u};
        if (ok) u = *reinterpret_cast<const uint4*>(&A[(size_t)arow*DD + k0]);
        if (psc){
          f[0]=bfu_lo(u.x); f[1]=bfu_hi(u.x); f[2]=bfu_lo(u.y); f[3]=bfu_hi(u.y);
          f[4]=bfu_lo(u.z); f[5]=bfu_hi(u.z); f[6]=bfu_lo(u.w); f[7]=bfu_hi(u.w);
          v8s av;
          #pragma unroll
          for (int j=0;j<8;++j)
            av[j] = (short)f2bf(fmaxf(fmaf(f[j], psc[k0+j], psh[k0+j]), 0.f));
          a[ks] = av;
        } else {
          a[ks] = *reinterpret_cast<v8s*>(&u);
        }
      }
    }
  }

  v4f acc[8];
  #pragma unroll
  for (int cg=0;cg<8;++cg) acc[cg] = (v4f){0.f,0.f,0.f,0.f};
  #pragma unroll
  for (int ks=0;ks<4;++ks){
    #pragma unroll
    for (int cg=0;cg<8;++cg){
      v8s b = *reinterpret_cast<const v8s*>(
                &Bt[(cg*16+l15)*DD + ks*32 + quad*8]);
      acc[cg] = __builtin_amdgcn_mfma_f32_16x16x32_bf16(a[ks], b, acc[cg], 0,0,0);
    }
  }

  float bc[8];
  #pragma unroll
  for (int cg=0;cg<8;++cg) bc[cg] = ldf(bias, cg*16 + l15, bfi);
  float ss[8], sq[8];
  #pragma unroll
  for (int cg=0;cg<8;++cg){ ss[cg]=0.f; sq[cg]=0.f; }

  #pragma unroll
  for (int reg=0;reg<4;++reg){
    const int row = R0 + quad*4 + reg;
    if (row < n){
      float degf = (mode==1) ? (float)deg[row] : 0.f;
      #pragma unroll
      for (int cg=0;cg<8;++cg){
        const int col = cg*16 + l15;
        float x = acc[cg][reg];
        if (mode==1) x = fmaf(degf, bc[cg], x) + ldf(H, (size_t)row*DD + col, bfi);
        else         x += bc[cg];
        out[(size_t)row*DD + col] = __float2bfloat16(x);
        ss[cg] += x; sq[cg] += x*x;
      }
    }
  }

  if (stats){
    #pragma unroll
    for (int cg=0;cg<8;++cg){
      float s = ss[cg], q = sq[cg];
      s += __shfl_xor(s, 16, 64); s += __shfl_xor(s, 32, 64);
      q += __shfl_xor(q, 16, 64); q += __shfl_xor(q, 32, 64);
      if (quad == 0){
        atomicAdd(&sb[cg*16 + l15], s);
        atomicAdd(&sb[128 + cg*16 + l15], q);
      }
    }
    __syncthreads();
    atomicAdd(&stats[t], sb[t]);
  }
}

__global__ void k_bn_params(const float* __restrict__ stats, const void* __restrict__ g,
                            const void* __restrict__ bb, const int* __restrict__ flags,
                            float inv_n, float* __restrict__ sc, float* __restrict__ sh){
  const int j = threadIdx.x;                // 128
  const int bf = flags[0];
  float mean = stats[j]*inv_n;
  float var  = stats[DD+j]*inv_n - mean*mean;
  float s = ldf(g, j, bf) * rsqrtf(var + 1e-5f);
  sc[j] = s;
  sh[j] = ldf(bb, j, bf) - mean*s;
}

__global__ void k_final(const unsigned* __restrict__ yH,
                        const float* __restrict__ sc, const float* __restrict__ sh,
                        int n, const int* __restrict__ flags, void* __restrict__ out){
  const int bf = flags[0];
  const int nw = n*64;
  for (int i = blockIdx.x*blockDim.x + threadIdx.x; i < nw;
       i += gridDim.x*blockDim.x){
    const int j0 = (i & 63)*2;
    unsigned u = yH[i];
    float v0 = fmaxf(fmaf(bfu_lo(u), sc[j0],   sh[j0]),   0.f);
    float v1 = fmaxf(fmaf(bfu_hi(u), sc[j0+1], sh[j0+1]), 0.f);
    if (bf){
      ((unsigned*)out)[i] = packbf(v0, v1);
    } else {
      *reinterpret_cast<float2*>((float*)out + 2*(size_t)i) = make_float2(v0, v1);
    }
  }
}

extern "C" void kernel_launch(void* const* d_in, const int* in_sizes, int n_in,
                              void* d_out, int out_size, void* d_ws, size_t ws_size,
                              hipStream_t stream)
{
  const void* h       = d_in[0];
  const int*  ei      = (const int*)d_in[1];
  const void* attr    = d_in[2];
  const void* ee_w1   = d_in[3];
  const void* ee_g1   = d_in[5];
  const void* ee_bb1  = d_in[6];
  const void* ee_w2   = d_in[7];
  const void* ee_b2   = d_in[8];
  const void* mlp_w1  = d_in[9];
  const void* mlp_b1  = d_in[10];
  const void* mlp_g1  = d_in[11];
  const void* mlp_bb1 = d_in[12];
  const void* mlp_w2  = d_in[13];
  const void* mlp_b2  = d_in[14];
  const void* mlp_g2  = d_in[15];
  const void* mlp_bb2 = d_in[16];

  const int N = in_sizes[0] / DD;
  const int E = in_sizes[1] / 2;
  const int nb = (N + 1023) / 1024;
  const int e64  = (E + 63) / 64;      // 64-slot edge windows
  const int e256 = (E + 64*WPB - 1) / (64*WPB);

  char* p = (char*)d_ws;
  auto alloc = [&](size_t bytes)->char*{
    char* r = p;
    p += (bytes + 255) & ~size_t(255);
    return r;
  };
  int* flags = (int*)alloc(8);
  // zero region: deg | csum(16) | Ssum(256) | stats1(256) | stats2(256) | Pagg
  char* zbase = p;
  int*   deg    = (int*)  zbase;
  float* csum   = (float*)(zbase + (size_t)N*4);
  float* Ssum   = (float*)(zbase + (size_t)N*4 + 64);
  float* stats1 = (float*)(zbase + (size_t)N*4 + 64 + 1024);
  float* stats2 = (float*)(zbase + (size_t)N*4 + 64 + 2048);
  float* Pagg   = (float*)(zbase + (size_t)N*4 + 64 + 3072);
  size_t zlen   = (size_t)N*4 + 64 + 3072 + (size_t)N*DD*4;
  p += (zlen + 255) & ~size_t(255);
  int*   bsum     = (int*)  alloc(256*4);
  int*   total    = (int*)  alloc(64);
  int*   offsets  = (int*)  alloc((size_t)(N+1)*4);
  int*   cursor   = (int*)  alloc((size_t)N*4);
  int*   win2node = (int*)  alloc((size_t)(e64 + 8)*4);
  int2*  se       = (int2*) alloc((size_t)E*8);
  short* Bt      = (short*)alloc((size_t)(3*DD*DD + DD*EDIM)*2);
  short* w1t     = Bt + 3*DD*DD;
  float* ebn_sc  = (float*)alloc(512);
  float* ebn_sh  = (float*)alloc(512);
  float* sc1     = (float*)alloc(512);
  float* sh1     = (float*)alloc(512);
  float* sc2     = (float*)alloc(512);
  float* sh2     = (float*)alloc(512);
  short* hnewH   = (short*)alloc((size_t)N*DD*2);
  short* zH      = (short*)alloc((size_t)N*DD*2);
  short* y1H     = (short*)alloc((size_t)N*DD*2);
  short* y2H     = (short*)alloc((size_t)N*DD*2);
  (void)ws_size; (void)n_in; (void)out_size;

  const int g64  = (N + 63) / 64;     // gemm grid
  const int gseg = (N + 15) / 16;     // gather grid (wave per node)

  hipMemsetAsync(zbase, 0, zlen, stream);
  k_detect<<<1, 1024, 0, stream>>>(ee_g1, ei, E, flags);
  k_transB<<<208, 256, 0, stream>>>(ee_w2, mlp_w1, mlp_w2, ee_w1, flags, Bt);
  k_attr_moments<<<256, 256, 0, stream>>>(attr, E, flags, Ssum, csum);
  k_edge_bn<<<1, 128, 0, stream>>>(ee_w1, ee_g1, ee_bb1, Ssum, csum,
                                   1.0f/(float)E, flags, ebn_sc, ebn_sh);
  k_hist<<<1024, 256, 0, stream>>>(ei, E, flags, deg);
  k_scan_partial<<<nb, 256, 0, stream>>>(deg, N, bsum);
  k_scan_tops<<<1, 256, 0, stream>>>(bsum, nb, total);
  k_scan_final<<<nb, 256, 0, stream>>>(deg, N, bsum, total, offsets, cursor,
                                       win2node);
  k_scatter<<<1024, 256, 0, stream>>>(ei, E, flags, cursor, se);

  // fused edge encoder + block-level node aggregate (f32 Pagg)
  k_edgeagg<<<e256, 256, 0, stream>>>(attr, se, w1t, ebn_sc, ebn_sh,
                                      offsets, win2node, flags, N, E, Pagg);

  // h_new = h + Pagg@ee_w2 + deg*ee_b2
  k_gemm_mfma<<<g64, 256, 0, stream>>>(nullptr, Pagg, Bt, ee_b2,
                                       nullptr, nullptr, deg, h, flags, N,
                                       (__hip_bfloat16*)hnewH, nullptr, 1);
  // z = h_new + gather
  k_gather_z<<<gseg, 256, 0, stream>>>((const uint4*)hnewH, offsets, se, N,
                                       (uint4*)zH);
  // y1 = z@mlp_w1 + b1 (+stats)
  k_gemm_mfma<<<g64, 256, 0, stream>>>(zH, nullptr, Bt + 16384, mlp_b1,
                                       nullptr, nullptr, nullptr, nullptr,
                                       flags, N, (__hip_bfloat16*)y1H, stats1, 0);
  k_bn_params<<<1, 128, 0, stream>>>(stats1, mlp_g1, mlp_bb1, flags,
                                     1.0f/(float)N, sc1, sh1);
  // y2 = relu(bn(y1))@mlp_w2 + b2 (+stats)
  k_gemm_mfma<<<g64, 256, 0, stream>>>(y1H, nullptr, Bt + 32768, mlp_b2,
                                       sc1, sh1, nullptr, nullptr,
                                       flags, N, (__hip_bfloat16*)y2H, stats2, 0);
  k_bn_params<<<1, 128, 0, stream>>>(stats2, mlp_g2, mlp_bb2, flags,
                                     1.0f/(float)N, sc2, sh2);

  k_final<<<2048, 256, 0, stream>>>((const unsigned*)y2H, sc2, sh2,
                                    N, flags, d_out);
}